// Round 3
// baseline (388.273 us; speedup 1.0000x reference)
//
#include <hip/hip_runtime.h>
#include <math.h>

// out[c,i] = W[i]^2 * sum_{e: iInd[e]=i} x[c, jInd[e]]   (B=1, C=32)
//
// Zero random-global-write pipeline:
//  1. transpose x [C,N] -> xt [N,C]  (contiguous 64/128B per node gather)
//  2. bin_edges: LDS-staged binning of (i&127,j) records into NB=ceil(N/128)
//     buckets; coalesced run flushes reserved via one atomicAdd per
//     (bucket,tile). No random 4B global writes.
//  3. accumulate: 2 blocks/bucket (16 channels each); LDS f32 accumulation
//     (ds_add_f32), W^2 applied per node, coalesced direct-to-out writes
//     (already in [C,N] layout -> no output transpose).
// Overflow (staging slots / bucket capacity) falls back to direct global
// atomics — correctness never depends on the Poisson bound.

#define TCH 32
#define BSHIFT 7
#define BNODES 128                  // nodes per bucket = 1<<BSHIFT
#define MAXNB 512                   // LDS sizing bound (N <= 65536)
#define SLOTS 32                    // staging slots per bucket per tile
#define BIN_THREADS 512
#define TILE 4096                   // edges per bin block
#define EPT (TILE / BIN_THREADS)
#define ACC_THREADS 256

__global__ void transpose_CN_to_NC(const float* __restrict__ x,
                                   float* __restrict__ xt, int N) {
    __shared__ float tile[32][33];
    const int n0 = blockIdx.x * 32;
    const int tx = threadIdx.x;
    const int ty = threadIdx.y;
    const int n = n0 + tx;
    if (n < N) tile[ty][tx] = x[(size_t)ty * N + n];
    __syncthreads();
    const int nw = n0 + ty;
    if (nw < N) xt[(size_t)nw * TCH + tx] = tile[tx][ty];
}

__device__ __forceinline__ void direct_update(float* out, const float* W,
                                              const float* x, int i, int j,
                                              int N) {
    const float w = W[i];
    const float w2 = w * w;
    for (int c = 0; c < TCH; ++c)
        atomicAdd(&out[(size_t)c * N + i], w2 * x[(size_t)c * N + j]);
}

__global__ __launch_bounds__(BIN_THREADS) void bin_edges(
    const int* __restrict__ iInd, const int* __restrict__ jInd,
    const float* __restrict__ W, const float* __restrict__ x,
    int* __restrict__ bins, int* __restrict__ gcursor,
    float* __restrict__ out, int E, int N, int NB, int cap) {
    __shared__ int stage[MAXNB * SLOTS];  // 64 KB
    __shared__ int scnt[MAXNB];
    __shared__ int incl[MAXNB];
    __shared__ int cntA[MAXNB];
    __shared__ int gbase[MAXNB];
    const int tid = threadIdx.x;

    scnt[tid] = 0;          // BIN_THREADS == MAXNB
    __syncthreads();

    const int e0 = blockIdx.x * TILE;
    for (int s = 0; s < EPT; ++s) {
        const int e = e0 + s * BIN_THREADS + tid;
        if (e < E) {
            const int i = iInd[e];
            const int j = jInd[e];
            const int b = i >> BSHIFT;
            const int slot = atomicAdd(&scnt[b], 1);
            if (slot < SLOTS) {
                stage[b * SLOTS + slot] = ((i & (BNODES - 1)) << 16) | j;
            } else {
                direct_update(out, W, x, i, j, N);  // ultra-rare
            }
        }
    }
    __syncthreads();

    int c_b = (tid < NB) ? min(scnt[tid], SLOTS) : 0;
    cntA[tid] = c_b;
    incl[tid] = c_b;
    __syncthreads();
    for (int off = 1; off < MAXNB; off <<= 1) {
        const int v = (tid >= off) ? incl[tid - off] : 0;
        __syncthreads();
        incl[tid] += v;
        __syncthreads();
    }
    if (tid < NB && c_b > 0) gbase[tid] = atomicAdd(&gcursor[tid], c_b);
    __syncthreads();

    const int total = incl[MAXNB - 1];
    for (int idx = tid; idx < total; idx += BIN_THREADS) {
        int lo = 0, hi = MAXNB - 1;
        while (lo < hi) {
            const int mid = (lo + hi) >> 1;
            if (incl[mid] > idx) hi = mid; else lo = mid + 1;
        }
        const int b = lo;
        const int k = idx - (incl[b] - cntA[b]);
        const int rec = stage[b * SLOTS + k];
        const int gslot = gbase[b] + k;
        if (gslot < cap) {
            bins[(size_t)b * cap + gslot] = rec;
        } else {
            const int i = (b << BSHIFT) | (rec >> 16);
            direct_update(out, W, x, i, rec & 0xFFFF, N);  // ultra-rare
        }
    }
}

__global__ __launch_bounds__(ACC_THREADS) void accumulate(
    const int* __restrict__ bins, const int* __restrict__ gcursor,
    const float* __restrict__ W, const float* __restrict__ xt,
    float* __restrict__ out, int N, int NB, int cap) {
    const int bucket = blockIdx.x >> 1;
    const int c0 = (blockIdx.x & 1) * 16;
    __shared__ float acc[BNODES][17];   // +1 pad: conflict-free final read
    for (int k = threadIdx.x; k < BNODES * 17; k += ACC_THREADS)
        (&acc[0][0])[k] = 0.f;
    __syncthreads();

    int cnt = gcursor[bucket];
    if (cnt > cap) cnt = cap;
    const int* rec = bins + (size_t)bucket * cap;
    const int cl = threadIdx.x & 15;   // channel lane
    const int rg = threadIdx.x >> 4;   // record group 0..15

    for (int r = rg; r < cnt; r += ACC_THREADS / 16) {
        const int pr = rec[r];
        const int j = pr & 0xFFFF;
        const int il = pr >> 16;
        const float v = xt[(size_t)j * TCH + c0 + cl];  // 64B contiguous / rec
        atomicAdd(&acc[il][cl], v);                     // ds_add_f32
    }
    __syncthreads();

    const int i0 = bucket << BSHIFT;
    for (int k = threadIdx.x; k < BNODES * 16; k += ACC_THREADS) {
        const int il = k & (BNODES - 1);
        const int c = k >> BSHIFT;
        const int i = i0 + il;
        if (i < N) {
            const float w = W[i];
            out[(size_t)(c0 + c) * N + i] += w * w * acc[il][c];
        }
    }
}

// ---- fallback (ws too small / N too big for record packing) ----
__global__ void edge_scatter_cn(const int* __restrict__ iInd,
                                const int* __restrict__ jInd,
                                const float* __restrict__ W,
                                const float* __restrict__ x,
                                float* __restrict__ out, int E, int N) {
    const long long t = (long long)blockIdx.x * blockDim.x + threadIdx.x;
    const int e = (int)(t >> 5);
    const int c = (int)(t & 31);
    if (e < E) {
        const int i = iInd[e];
        const int j = jInd[e];
        const float w = W[i];
        atomicAdd(&out[(size_t)c * N + i], w * w * x[(size_t)c * N + j]);
    }
}

extern "C" void kernel_launch(void* const* d_in, const int* in_sizes, int n_in,
                              void* d_out, int out_size, void* d_ws, size_t ws_size,
                              hipStream_t stream) {
    const float* x    = (const float*)d_in[0];   // [1, C, N]
    const float* W    = (const float*)d_in[1];   // [N]
    const int*   iInd = (const int*)d_in[2];     // [E]
    const int*   jInd = (const int*)d_in[3];     // [E]

    const int N = in_sizes[1];
    const int E = in_sizes[2];
    float* out = (float*)d_out;

    const int NB = (N + BNODES - 1) >> BSHIFT;
    const int mean = (NB > 0) ? (E / NB) : 0;
    const int cap = mean + (int)(8.0 * sqrt((double)(mean > 0 ? mean : 1))) + 64;

    const size_t algn = 64;
    const size_t xt_elems  = (((size_t)N * TCH) + algn - 1) / algn * algn;
    const size_t bin_elems = (((size_t)NB * cap) + algn - 1) / algn * algn;
    const size_t cur_elems = (((size_t)NB) + algn - 1) / algn * algn;
    const size_t need = (xt_elems + bin_elems + cur_elems) * 4;

    if (ws_size >= need && NB <= MAXNB && N <= 65536) {
        float* xt      = (float*)d_ws;
        int*   bins    = (int*)(xt + xt_elems);
        int*   gcursor = bins + bin_elems;

        hipMemsetAsync(out, 0, (size_t)out_size * sizeof(float), stream);
        hipMemsetAsync(gcursor, 0, (size_t)NB * sizeof(int), stream);

        const int ntiles = (N + 31) / 32;
        dim3 tb(32, 32);
        transpose_CN_to_NC<<<ntiles, tb, 0, stream>>>(x, xt, N);

        const int bin_blocks = (E + TILE - 1) / TILE;
        bin_edges<<<bin_blocks, BIN_THREADS, 0, stream>>>(
            iInd, jInd, W, x, bins, gcursor, out, E, N, NB, cap);

        accumulate<<<NB * 2, ACC_THREADS, 0, stream>>>(
            bins, gcursor, W, xt, out, N, NB, cap);
    } else {
        hipMemsetAsync(out, 0, (size_t)out_size * sizeof(float), stream);
        const int threads = 256;
        const long long total = (long long)E * TCH;
        const int blocks = (int)((total + threads - 1) / threads);
        edge_scatter_cn<<<blocks, threads, 0, stream>>>(iInd, jInd, W, x, out, E, N);
    }
}

// Round 4
// 331.967 us; speedup vs baseline: 1.1696x; 1.1696x over previous
//
#include <hip/hip_runtime.h>
#include <math.h>

// out[c,i] = W[i]^2 * sum_{e: iInd[e]=i} x[c, jInd[e]]   (B=1, C=32)
//
// Pipeline:
//  1. transpose x [C,N] -> xt [N,C]
//  2. bin_edges: LDS-staged binning of (i&127,j) records into NB buckets,
//     coalesced run flushes (one int atomic per bucket-tile).
//  3. accumulate2: NB*SPLIT blocks; each block owns a contiguous chunk of one
//     bucket's records; 8 groups x 32 lanes (lane=channel), 2-way unrolled
//     128B gathers from xt, LDS f32 accumulation. Flush = coalesced partial
//     slab write (no atomics), or w^2-scaled global atomics if ws is small.
//  4. reduce_partial: sum SPLIT partials, apply W^2, add into out (coalesced).
// Overflows fall back to direct global atomics into out (pre-zeroed).

#define TCH 32
#define BSHIFT 7
#define BNODES 128
#define MAXNB 512
#define SLOTS 32
#define BIN_THREADS 512
#define TILE 4096
#define EPT (TILE / BIN_THREADS)
#define ACC_THREADS 256

__global__ void transpose_CN_to_NC(const float* __restrict__ x,
                                   float* __restrict__ xt, int N) {
    __shared__ float tile[32][33];
    const int n0 = blockIdx.x * 32;
    const int tx = threadIdx.x;
    const int ty = threadIdx.y;
    const int n = n0 + tx;
    if (n < N) tile[ty][tx] = x[(size_t)ty * N + n];
    __syncthreads();
    const int nw = n0 + ty;
    if (nw < N) xt[(size_t)nw * TCH + tx] = tile[tx][ty];
}

__device__ __forceinline__ void direct_update(float* out, const float* W,
                                              const float* x, int i, int j,
                                              int N) {
    const float w = W[i];
    const float w2 = w * w;
    for (int c = 0; c < TCH; ++c)
        atomicAdd(&out[(size_t)c * N + i], w2 * x[(size_t)c * N + j]);
}

__global__ __launch_bounds__(BIN_THREADS) void bin_edges(
    const int* __restrict__ iInd, const int* __restrict__ jInd,
    const float* __restrict__ W, const float* __restrict__ x,
    int* __restrict__ bins, int* __restrict__ gcursor,
    float* __restrict__ out, int E, int N, int NB, int cap) {
    __shared__ int stage[MAXNB * SLOTS];  // 64 KB
    __shared__ int scnt[MAXNB];
    __shared__ int incl[MAXNB];
    __shared__ int cntA[MAXNB];
    __shared__ int gbase[MAXNB];
    const int tid = threadIdx.x;

    scnt[tid] = 0;  // BIN_THREADS == MAXNB
    __syncthreads();

    const int e0 = blockIdx.x * TILE;
    for (int s = 0; s < EPT; ++s) {
        const int e = e0 + s * BIN_THREADS + tid;
        if (e < E) {
            const int i = iInd[e];
            const int j = jInd[e];
            const int b = i >> BSHIFT;
            const int slot = atomicAdd(&scnt[b], 1);
            if (slot < SLOTS) {
                stage[b * SLOTS + slot] = ((i & (BNODES - 1)) << 16) | j;
            } else {
                direct_update(out, W, x, i, j, N);  // ultra-rare
            }
        }
    }
    __syncthreads();

    int c_b = (tid < NB) ? min(scnt[tid], SLOTS) : 0;
    cntA[tid] = c_b;
    incl[tid] = c_b;
    __syncthreads();
    for (int off = 1; off < MAXNB; off <<= 1) {
        const int v = (tid >= off) ? incl[tid - off] : 0;
        __syncthreads();
        incl[tid] += v;
        __syncthreads();
    }
    if (tid < NB && c_b > 0) gbase[tid] = atomicAdd(&gcursor[tid], c_b);
    __syncthreads();

    const int total = incl[MAXNB - 1];
    for (int idx = tid; idx < total; idx += BIN_THREADS) {
        int lo = 0, hi = MAXNB - 1;
        while (lo < hi) {
            const int mid = (lo + hi) >> 1;
            if (incl[mid] > idx) hi = mid; else lo = mid + 1;
        }
        const int b = lo;
        const int k = idx - (incl[b] - cntA[b]);
        const int rec = stage[b * SLOTS + k];
        const int gslot = gbase[b] + k;
        if (gslot < cap) {
            bins[(size_t)b * cap + gslot] = rec;
        } else {
            const int i = (b << BSHIFT) | (rec >> 16);
            direct_update(out, W, x, i, rec & 0xFFFF, N);  // ultra-rare
        }
    }
}

// NB*SPLIT blocks; block = 8 groups x 32 lanes. lane = channel.
__global__ __launch_bounds__(ACC_THREADS) void accumulate2(
    const int* __restrict__ bins, const int* __restrict__ gcursor,
    const float* __restrict__ xt, const float* __restrict__ W,
    float* __restrict__ partial, float* __restrict__ out,
    int N, int cap, int SPLIT, int use_partial) {
    const int bucket = blockIdx.x / SPLIT;
    const int split  = blockIdx.x - bucket * SPLIT;
    __shared__ float acc[BNODES * 33];
    for (int k = threadIdx.x; k < BNODES * 33; k += ACC_THREADS) acc[k] = 0.f;
    __syncthreads();

    int cnt = gcursor[bucket];
    if (cnt > cap) cnt = cap;
    const int* rec = bins + (size_t)bucket * cap;
    const int chunk = (cnt + SPLIT - 1) / SPLIT;
    const int r0 = split * chunk;
    const int r1 = min(cnt, r0 + chunk);

    const int c = threadIdx.x & 31;      // channel
    const int g = threadIdx.x >> 5;      // group 0..7
    const int stride = ACC_THREADS / 32; // 8

    int r = r0 + g;
    for (; r + stride < r1; r += 2 * stride) {
        const int pr0 = rec[r];
        const int pr1 = rec[r + stride];
        const float v0 = xt[(size_t)(pr0 & 0xFFFF) * TCH + c];
        const float v1 = xt[(size_t)(pr1 & 0xFFFF) * TCH + c];
        atomicAdd(&acc[(pr0 >> 16) * 33 + c], v0);
        atomicAdd(&acc[(pr1 >> 16) * 33 + c], v1);
    }
    if (r < r1) {
        const int pr = rec[r];
        atomicAdd(&acc[(pr >> 16) * 33 + c],
                  xt[(size_t)(pr & 0xFFFF) * TCH + c]);
    }
    __syncthreads();

    if (use_partial) {
        float* p = partial + (size_t)blockIdx.x * (BNODES * TCH);
        for (int k = threadIdx.x; k < BNODES * TCH; k += ACC_THREADS) {
            const int il = k & (BNODES - 1);
            const int cc = k >> BSHIFT;
            p[k] = acc[il * 33 + cc];  // [c][il] layout, coalesced
        }
    } else {
        const int i0 = bucket << BSHIFT;
        for (int k = threadIdx.x; k < BNODES * TCH; k += ACC_THREADS) {
            const int il = k & (BNODES - 1);
            const int cc = k >> BSHIFT;
            const int i = i0 + il;
            if (i < N) {
                const float v = acc[il * 33 + cc];
                if (v != 0.f) {
                    const float w = W[i];
                    atomicAdd(&out[(size_t)cc * N + i], w * w * v);
                }
            }
        }
    }
}

// grid: ((N+255)/256, 32); adds W^2 * sum(partials) into out.
__global__ void reduce_partial(const float* __restrict__ partial,
                               const float* __restrict__ W,
                               float* __restrict__ out, int N, int SPLIT) {
    const int i = blockIdx.x * 256 + threadIdx.x;
    const int c = blockIdx.y;
    if (i >= N) return;
    const int bucket = i >> BSHIFT;
    const int il = i & (BNODES - 1);
    const float* p = partial + (size_t)bucket * SPLIT * (BNODES * TCH)
                             + (size_t)c * BNODES + il;
    float s = 0.f;
    for (int sp = 0; sp < SPLIT; ++sp) s += p[(size_t)sp * (BNODES * TCH)];
    const float w = W[i];
    out[(size_t)c * N + i] += w * w * s;
}

// ---- fallback (ws too small / N too big for record packing) ----
__global__ void edge_scatter_cn(const int* __restrict__ iInd,
                                const int* __restrict__ jInd,
                                const float* __restrict__ W,
                                const float* __restrict__ x,
                                float* __restrict__ out, int E, int N) {
    const long long t = (long long)blockIdx.x * blockDim.x + threadIdx.x;
    const int e = (int)(t >> 5);
    const int c = (int)(t & 31);
    if (e < E) {
        const int i = iInd[e];
        const int j = jInd[e];
        const float w = W[i];
        atomicAdd(&out[(size_t)c * N + i], w * w * x[(size_t)c * N + j]);
    }
}

extern "C" void kernel_launch(void* const* d_in, const int* in_sizes, int n_in,
                              void* d_out, int out_size, void* d_ws, size_t ws_size,
                              hipStream_t stream) {
    const float* x    = (const float*)d_in[0];   // [1, C, N]
    const float* W    = (const float*)d_in[1];   // [N]
    const int*   iInd = (const int*)d_in[2];     // [E]
    const int*   jInd = (const int*)d_in[3];     // [E]

    const int N = in_sizes[1];
    const int E = in_sizes[2];
    float* out = (float*)d_out;

    const int NB = (N + BNODES - 1) >> BSHIFT;
    const int mean = (NB > 0) ? (E / NB) : 0;
    const int cap = mean + (int)(8.0 * sqrt((double)(mean > 0 ? mean : 1))) + 64;

    const size_t algn = 64;
    const size_t xt_elems  = (((size_t)N * TCH) + algn - 1) / algn * algn;
    const size_t bin_elems = (((size_t)NB * cap) + algn - 1) / algn * algn;
    const size_t cur_elems = (((size_t)NB) + algn - 1) / algn * algn;
    const size_t base_need = (xt_elems + bin_elems + cur_elems) * 4;

    if (ws_size >= base_need && NB <= MAXNB && N <= 65536) {
        float* xt      = (float*)d_ws;
        int*   bins    = (int*)(xt + xt_elems);
        int*   gcursor = bins + bin_elems;
        float* partial = (float*)(gcursor + cur_elems);

        int SPLIT = 8, use_partial = 0;
        for (int s = 8; s >= 2; s >>= 1) {
            const size_t pe = (size_t)NB * s * BNODES * TCH;
            if (base_need + pe * 4 <= ws_size) {
                SPLIT = s; use_partial = 1; break;
            }
        }

        hipMemsetAsync(out, 0, (size_t)out_size * sizeof(float), stream);
        hipMemsetAsync(gcursor, 0, (size_t)NB * sizeof(int), stream);

        const int ntiles = (N + 31) / 32;
        dim3 tb(32, 32);
        transpose_CN_to_NC<<<ntiles, tb, 0, stream>>>(x, xt, N);

        const int bin_blocks = (E + TILE - 1) / TILE;
        bin_edges<<<bin_blocks, BIN_THREADS, 0, stream>>>(
            iInd, jInd, W, x, bins, gcursor, out, E, N, NB, cap);

        accumulate2<<<NB * SPLIT, ACC_THREADS, 0, stream>>>(
            bins, gcursor, xt, W, partial, out, N, cap, SPLIT, use_partial);

        if (use_partial) {
            dim3 rg((N + 255) / 256, TCH);
            reduce_partial<<<rg, 256, 0, stream>>>(partial, W, out, N, SPLIT);
        }
    } else {
        hipMemsetAsync(out, 0, (size_t)out_size * sizeof(float), stream);
        const int threads = 256;
        const long long total = (long long)E * TCH;
        const int blocks = (int)((total + threads - 1) / threads);
        edge_scatter_cn<<<blocks, threads, 0, stream>>>(iInd, jInd, W, x, out, E, N);
    }
}

// Round 5
// 330.927 us; speedup vs baseline: 1.1733x; 1.0031x over previous
//
#include <hip/hip_runtime.h>
#include <math.h>

// out[c,i] = W[i]^2 * sum_{e: iInd[e]=i} x[c, jInd[e]]   (B=1, C=32)
//
// Pipeline:
//  1. transpose x [C,N] -> xt [N,C]
//  2. bin_edges: LDS-staged binning of (i&127,j) records into NB buckets,
//     coalesced run flushes (one int atomic per bucket-tile).
//  3. accumulate2: NB*SPLIT blocks, 8 groups x 32 lanes (lane=channel).
//     8-deep unrolled record batch -> 8 independent 128B gathers in flight
//     per group -> LDS f32 accumulation. Flush partials coalesced (no
//     atomics) or w^2-scaled global atomics if ws is small.
//  4. reduce_partial: sum SPLIT partials, apply W^2, add into out.
// Overflows fall back to direct global atomics into out (pre-zeroed).

#define TCH 32
#define BSHIFT 7
#define BNODES 128
#define MAXNB 512
#define SLOTS 32
#define BIN_THREADS 512
#define TILE 4096
#define EPT (TILE / BIN_THREADS)
#define ACC_THREADS 256
#define UNR 8

__global__ void transpose_CN_to_NC(const float* __restrict__ x,
                                   float* __restrict__ xt, int N) {
    __shared__ float tile[32][33];
    const int n0 = blockIdx.x * 32;
    const int tx = threadIdx.x;
    const int ty = threadIdx.y;
    const int n = n0 + tx;
    if (n < N) tile[ty][tx] = x[(size_t)ty * N + n];
    __syncthreads();
    const int nw = n0 + ty;
    if (nw < N) xt[(size_t)nw * TCH + tx] = tile[tx][ty];
}

__device__ __forceinline__ void direct_update(float* out, const float* W,
                                              const float* x, int i, int j,
                                              int N) {
    const float w = W[i];
    const float w2 = w * w;
    for (int c = 0; c < TCH; ++c)
        atomicAdd(&out[(size_t)c * N + i], w2 * x[(size_t)c * N + j]);
}

__global__ __launch_bounds__(BIN_THREADS) void bin_edges(
    const int* __restrict__ iInd, const int* __restrict__ jInd,
    const float* __restrict__ W, const float* __restrict__ x,
    int* __restrict__ bins, int* __restrict__ gcursor,
    float* __restrict__ out, int E, int N, int NB, int cap) {
    __shared__ int stage[MAXNB * SLOTS];  // 64 KB
    __shared__ int scnt[MAXNB];
    __shared__ int incl[MAXNB];
    __shared__ int cntA[MAXNB];
    __shared__ int gbase[MAXNB];
    const int tid = threadIdx.x;

    scnt[tid] = 0;  // BIN_THREADS == MAXNB
    __syncthreads();

    const int e0 = blockIdx.x * TILE;
    for (int s = 0; s < EPT; ++s) {
        const int e = e0 + s * BIN_THREADS + tid;
        if (e < E) {
            const int i = iInd[e];
            const int j = jInd[e];
            const int b = i >> BSHIFT;
            const int slot = atomicAdd(&scnt[b], 1);
            if (slot < SLOTS) {
                stage[b * SLOTS + slot] = ((i & (BNODES - 1)) << 16) | j;
            } else {
                direct_update(out, W, x, i, j, N);  // ultra-rare
            }
        }
    }
    __syncthreads();

    int c_b = (tid < NB) ? min(scnt[tid], SLOTS) : 0;
    cntA[tid] = c_b;
    incl[tid] = c_b;
    __syncthreads();
    for (int off = 1; off < MAXNB; off <<= 1) {
        const int v = (tid >= off) ? incl[tid - off] : 0;
        __syncthreads();
        incl[tid] += v;
        __syncthreads();
    }
    if (tid < NB && c_b > 0) gbase[tid] = atomicAdd(&gcursor[tid], c_b);
    __syncthreads();

    const int total = incl[MAXNB - 1];
    for (int idx = tid; idx < total; idx += BIN_THREADS) {
        int lo = 0, hi = MAXNB - 1;
        while (lo < hi) {
            const int mid = (lo + hi) >> 1;
            if (incl[mid] > idx) hi = mid; else lo = mid + 1;
        }
        const int b = lo;
        const int k = idx - (incl[b] - cntA[b]);
        const int rec = stage[b * SLOTS + k];
        const int gslot = gbase[b] + k;
        if (gslot < cap) {
            bins[(size_t)b * cap + gslot] = rec;
        } else {
            const int i = (b << BSHIFT) | (rec >> 16);
            direct_update(out, W, x, i, rec & 0xFFFF, N);  // ultra-rare
        }
    }
}

// NB*SPLIT blocks; block = 8 groups x 32 lanes. lane = channel.
// 8-deep unroll: 8 independent gathers in flight per group.
__global__ __launch_bounds__(ACC_THREADS) void accumulate2(
    const int* __restrict__ bins, const int* __restrict__ gcursor,
    const float* __restrict__ xt, const float* __restrict__ W,
    float* __restrict__ partial, float* __restrict__ out,
    int N, int cap, int SPLIT, int use_partial) {
    const int bucket = blockIdx.x / SPLIT;
    const int split  = blockIdx.x - bucket * SPLIT;
    __shared__ float acc[BNODES * 33];
    for (int k = threadIdx.x; k < BNODES * 33; k += ACC_THREADS) acc[k] = 0.f;
    __syncthreads();

    int cnt = gcursor[bucket];
    if (cnt > cap) cnt = cap;
    const int* rec = bins + (size_t)bucket * cap;
    const int chunk = (cnt + SPLIT - 1) / SPLIT;
    const int r0 = split * chunk;
    const int r1 = min(cnt, r0 + chunk);

    const int c = threadIdx.x & 31;      // channel
    const int g = threadIdx.x >> 5;      // group 0..7
    const int stride = ACC_THREADS / 32; // 8

    int r = r0 + g;
    // main loop: UNR records per group per iteration, all independent
    for (; r + (UNR - 1) * stride < r1; r += UNR * stride) {
        int pr0 = __builtin_nontemporal_load(&rec[r + 0 * stride]);
        int pr1 = __builtin_nontemporal_load(&rec[r + 1 * stride]);
        int pr2 = __builtin_nontemporal_load(&rec[r + 2 * stride]);
        int pr3 = __builtin_nontemporal_load(&rec[r + 3 * stride]);
        int pr4 = __builtin_nontemporal_load(&rec[r + 4 * stride]);
        int pr5 = __builtin_nontemporal_load(&rec[r + 5 * stride]);
        int pr6 = __builtin_nontemporal_load(&rec[r + 6 * stride]);
        int pr7 = __builtin_nontemporal_load(&rec[r + 7 * stride]);
        float v0 = xt[(size_t)(pr0 & 0xFFFF) * TCH + c];
        float v1 = xt[(size_t)(pr1 & 0xFFFF) * TCH + c];
        float v2 = xt[(size_t)(pr2 & 0xFFFF) * TCH + c];
        float v3 = xt[(size_t)(pr3 & 0xFFFF) * TCH + c];
        float v4 = xt[(size_t)(pr4 & 0xFFFF) * TCH + c];
        float v5 = xt[(size_t)(pr5 & 0xFFFF) * TCH + c];
        float v6 = xt[(size_t)(pr6 & 0xFFFF) * TCH + c];
        float v7 = xt[(size_t)(pr7 & 0xFFFF) * TCH + c];
        atomicAdd(&acc[(pr0 >> 16) * 33 + c], v0);
        atomicAdd(&acc[(pr1 >> 16) * 33 + c], v1);
        atomicAdd(&acc[(pr2 >> 16) * 33 + c], v2);
        atomicAdd(&acc[(pr3 >> 16) * 33 + c], v3);
        atomicAdd(&acc[(pr4 >> 16) * 33 + c], v4);
        atomicAdd(&acc[(pr5 >> 16) * 33 + c], v5);
        atomicAdd(&acc[(pr6 >> 16) * 33 + c], v6);
        atomicAdd(&acc[(pr7 >> 16) * 33 + c], v7);
    }
    for (; r < r1; r += stride) {
        const int pr = __builtin_nontemporal_load(&rec[r]);
        atomicAdd(&acc[(pr >> 16) * 33 + c],
                  xt[(size_t)(pr & 0xFFFF) * TCH + c]);
    }
    __syncthreads();

    if (use_partial) {
        float* p = partial + (size_t)blockIdx.x * (BNODES * TCH);
        for (int k = threadIdx.x; k < BNODES * TCH; k += ACC_THREADS) {
            const int il = k & (BNODES - 1);
            const int cc = k >> BSHIFT;
            p[k] = acc[il * 33 + cc];  // [c][il] layout, coalesced
        }
    } else {
        const int i0 = bucket << BSHIFT;
        for (int k = threadIdx.x; k < BNODES * TCH; k += ACC_THREADS) {
            const int il = k & (BNODES - 1);
            const int cc = k >> BSHIFT;
            const int i = i0 + il;
            if (i < N) {
                const float v = acc[il * 33 + cc];
                if (v != 0.f) {
                    const float w = W[i];
                    atomicAdd(&out[(size_t)cc * N + i], w * w * v);
                }
            }
        }
    }
}

// grid: ((N+255)/256, 32); adds W^2 * sum(partials) into out.
__global__ void reduce_partial(const float* __restrict__ partial,
                               const float* __restrict__ W,
                               float* __restrict__ out, int N, int SPLIT) {
    const int i = blockIdx.x * 256 + threadIdx.x;
    const int c = blockIdx.y;
    if (i >= N) return;
    const int bucket = i >> BSHIFT;
    const int il = i & (BNODES - 1);
    const float* p = partial + (size_t)bucket * SPLIT * (BNODES * TCH)
                             + (size_t)c * BNODES + il;
    float s = 0.f;
    for (int sp = 0; sp < SPLIT; ++sp) s += p[(size_t)sp * (BNODES * TCH)];
    const float w = W[i];
    out[(size_t)c * N + i] += w * w * s;
}

// ---- fallback (ws too small / N too big for record packing) ----
__global__ void edge_scatter_cn(const int* __restrict__ iInd,
                                const int* __restrict__ jInd,
                                const float* __restrict__ W,
                                const float* __restrict__ x,
                                float* __restrict__ out, int E, int N) {
    const long long t = (long long)blockIdx.x * blockDim.x + threadIdx.x;
    const int e = (int)(t >> 5);
    const int c = (int)(t & 31);
    if (e < E) {
        const int i = iInd[e];
        const int j = jInd[e];
        const float w = W[i];
        atomicAdd(&out[(size_t)c * N + i], w * w * x[(size_t)c * N + j]);
    }
}

extern "C" void kernel_launch(void* const* d_in, const int* in_sizes, int n_in,
                              void* d_out, int out_size, void* d_ws, size_t ws_size,
                              hipStream_t stream) {
    const float* x    = (const float*)d_in[0];   // [1, C, N]
    const float* W    = (const float*)d_in[1];   // [N]
    const int*   iInd = (const int*)d_in[2];     // [E]
    const int*   jInd = (const int*)d_in[3];     // [E]

    const int N = in_sizes[1];
    const int E = in_sizes[2];
    float* out = (float*)d_out;

    const int NB = (N + BNODES - 1) >> BSHIFT;
    const int mean = (NB > 0) ? (E / NB) : 0;
    const int cap = mean + (int)(8.0 * sqrt((double)(mean > 0 ? mean : 1))) + 64;

    const size_t algn = 64;
    const size_t xt_elems  = (((size_t)N * TCH) + algn - 1) / algn * algn;
    const size_t bin_elems = (((size_t)NB * cap) + algn - 1) / algn * algn;
    const size_t cur_elems = (((size_t)NB) + algn - 1) / algn * algn;
    const size_t base_need = (xt_elems + bin_elems + cur_elems) * 4;

    if (ws_size >= base_need && NB <= MAXNB && N <= 65536) {
        float* xt      = (float*)d_ws;
        int*   bins    = (int*)(xt + xt_elems);
        int*   gcursor = bins + bin_elems;
        float* partial = (float*)(gcursor + cur_elems);

        int SPLIT = 8, use_partial = 0;
        for (int s = 8; s >= 2; s >>= 1) {
            const size_t pe = (size_t)NB * s * BNODES * TCH;
            if (base_need + pe * 4 <= ws_size) {
                SPLIT = s; use_partial = 1; break;
            }
        }

        hipMemsetAsync(out, 0, (size_t)out_size * sizeof(float), stream);
        hipMemsetAsync(gcursor, 0, (size_t)NB * sizeof(int), stream);

        const int ntiles = (N + 31) / 32;
        dim3 tb(32, 32);
        transpose_CN_to_NC<<<ntiles, tb, 0, stream>>>(x, xt, N);

        const int bin_blocks = (E + TILE - 1) / TILE;
        bin_edges<<<bin_blocks, BIN_THREADS, 0, stream>>>(
            iInd, jInd, W, x, bins, gcursor, out, E, N, NB, cap);

        accumulate2<<<NB * SPLIT, ACC_THREADS, 0, stream>>>(
            bins, gcursor, xt, W, partial, out, N, cap, SPLIT, use_partial);

        if (use_partial) {
            dim3 rg((N + 255) / 256, TCH);
            reduce_partial<<<rg, 256, 0, stream>>>(partial, W, out, N, SPLIT);
        }
    } else {
        hipMemsetAsync(out, 0, (size_t)out_size * sizeof(float), stream);
        const int threads = 256;
        const long long total = (long long)E * TCH;
        const int blocks = (int)((total + threads - 1) / threads);
        edge_scatter_cn<<<blocks, threads, 0, stream>>>(iInd, jInd, W, x, out, E, N);
    }
}